// Round 1
// baseline (370.383 us; speedup 1.0000x reference)
//
#include <hip/hip_runtime.h>

#define BEV_H 512
#define BEV_W 512
#define HW (BEV_H * BEV_W)   // 262144 = 2^18
#define C_CH 64
#define OVF_CAP 131072

// ---- Pass 2: per-pillar build of cell -> first-pillar map (+overflow list) ----
__global__ __launch_bounds__(256) void pp_build(
    const int2* __restrict__ coords, int* __restrict__ counts,
    int* __restrict__ first, int* __restrict__ ovf_cnt, int2* __restrict__ ovf,
    int total, int P) {
  int tid = blockIdx.x * 256 + threadIdx.x;
  if (tid >= total) return;
  int b = tid / P;
  int2 yx = coords[tid];
  int y = min(max(yx.x, 0), BEV_H - 1);
  int x = min(max(yx.y, 0), BEV_W - 1);
  int cell = (b << 18) | (y << 9) | x;
  int old = atomicAdd(&counts[cell], 1);
  if (old == 0) {
    first[cell] = tid;  // global pillar id
  } else {
    int slot = atomicAdd(ovf_cnt, 1);
    if (slot < OVF_CAP) ovf[slot] = make_int2(tid, cell);
  }
}

// ---- Pass 3: gather-write. Thread = 4 consecutive cells x 64 channels. ----
// Predicated float4 feature loads, register transpose, coalesced float4 stores.
__global__ __launch_bounds__(256) void pp_write(
    const int4* __restrict__ counts4, const int4* __restrict__ first4,
    const float* __restrict__ feats, float* __restrict__ out, int nthreads) {
  int g = blockIdx.x * 256 + threadIdx.x;
  if (g >= nthreads) return;
  size_t cell0 = (size_t)g * 4;
  int b = (int)(cell0 >> 18);
  int flat0 = (int)(cell0 & (HW - 1));
  int4 cnt = counts4[g];
  int4 fst = first4[g];
  // sanitize indices for empty cells (avoid wild pointer formation)
  int i0 = cnt.x > 0 ? fst.x : 0;
  int i1 = cnt.y > 0 ? fst.y : 0;
  int i2 = cnt.z > 0 ? fst.z : 0;
  int i3 = cnt.w > 0 ? fst.w : 0;
  const float4* p0 = (const float4*)feats + (size_t)i0 * 16;
  const float4* p1 = (const float4*)feats + (size_t)i1 * 16;
  const float4* p2 = (const float4*)feats + (size_t)i2 * 16;
  const float4* p3 = (const float4*)feats + (size_t)i3 * 16;
  float* outb = out + (size_t)b * C_CH * HW + flat0;
#pragma unroll 4
  for (int cq = 0; cq < 16; ++cq) {
    float4 f0 = make_float4(0.f, 0.f, 0.f, 0.f);
    float4 f1 = f0, f2 = f0, f3 = f0;
    if (cnt.x > 0) f0 = p0[cq];
    if (cnt.y > 0) f1 = p1[cq];
    if (cnt.z > 0) f2 = p2[cq];
    if (cnt.w > 0) f3 = p3[cq];
    float* o = outb + (size_t)(cq * 4) * HW;
    *(float4*)(o)                    = make_float4(f0.x, f1.x, f2.x, f3.x);
    *(float4*)(o + (size_t)HW)       = make_float4(f0.y, f1.y, f2.y, f3.y);
    *(float4*)(o + (size_t)2 * HW)   = make_float4(f0.z, f1.z, f2.z, f3.z);
    *(float4*)(o + (size_t)3 * HW)   = make_float4(f0.w, f1.w, f2.w, f3.w);
  }
}

// ---- Pass 4: rare duplicate pillars -> direct atomic add into out ----
__global__ __launch_bounds__(256) void pp_ovf(
    const int* __restrict__ ovf_cnt, const int2* __restrict__ ovf,
    const float* __restrict__ feats, float* __restrict__ out) {
  int n = *ovf_cnt;
  n = min(n, OVF_CAP);
  int total = n * C_CH;
  int stride = gridDim.x * blockDim.x;
  for (int idx = blockIdx.x * blockDim.x + threadIdx.x; idx < total; idx += stride) {
    int e = idx >> 6;
    int c = idx & 63;
    int2 ent = ovf[e];
    int b = ent.y >> 18;
    int flat = ent.y & (HW - 1);
    atomicAdd(out + (((size_t)(b * C_CH + c)) << 18) + flat,
              feats[(size_t)ent.x * C_CH + c]);
  }
}

// ---- Fallback path (if ws too small): zero + direct atomic scatter ----
__global__ __launch_bounds__(256) void pp_zero(float4* __restrict__ out, int n4) {
  int stride = gridDim.x * blockDim.x;
  for (int i = blockIdx.x * blockDim.x + threadIdx.x; i < n4; i += stride)
    out[i] = make_float4(0.f, 0.f, 0.f, 0.f);
}

__global__ __launch_bounds__(256) void pp_direct(
    const int2* __restrict__ coords, const float* __restrict__ feats,
    float* __restrict__ out, int total, int P) {
  int idx = blockIdx.x * 256 + threadIdx.x;
  if (idx >= total * C_CH) return;
  int tid = idx >> 6;
  int c = idx & 63;
  int b = tid / P;
  int2 yx = coords[tid];
  int y = min(max(yx.x, 0), BEV_H - 1);
  int x = min(max(yx.y, 0), BEV_W - 1);
  int flat = (y << 9) | x;
  atomicAdd(out + (((size_t)(b * C_CH + c)) << 18) + flat,
            feats[(size_t)tid * C_CH + c]);
}

extern "C" void kernel_launch(void* const* d_in, const int* in_sizes, int n_in,
                              void* d_out, int out_size, void* d_ws, size_t ws_size,
                              hipStream_t stream) {
  const float* feats = (const float*)d_in[0];
  const int* coords = (const int*)d_in[1];
  float* out = (float*)d_out;

  const int B = out_size / (C_CH * HW);    // 4
  const int totalP = in_sizes[1] / 2;      // B*P = 120000
  const int P = totalP / B;                // 30000

  const size_t counts_bytes = (size_t)B * HW * sizeof(int);   // 4 MB
  const size_t off_ovfcnt = counts_bytes;
  const size_t off_first = off_ovfcnt + 16;                   // keep 16B alignment
  const size_t off_ovf = off_first + counts_bytes;
  const size_t needed = off_ovf + (size_t)OVF_CAP * sizeof(int2);

  if (ws_size >= needed) {
    int* counts = (int*)((char*)d_ws);
    int* ovf_cnt = (int*)((char*)d_ws + off_ovfcnt);
    int* first = (int*)((char*)d_ws + off_first);
    int2* ovf = (int2*)((char*)d_ws + off_ovf);

    // zero counts + overflow counter (ws is re-poisoned before every call)
    hipMemsetAsync(d_ws, 0, off_ovfcnt + 16, stream);

    int blocks_b = (totalP + 255) / 256;
    pp_build<<<blocks_b, 256, 0, stream>>>((const int2*)coords, counts, first,
                                           ovf_cnt, ovf, totalP, P);

    int nth = B * HW / 4;  // 262144 threads
    pp_write<<<nth / 256, 256, 0, stream>>>((const int4*)counts,
                                            (const int4*)first, feats, out, nth);

    pp_ovf<<<256, 256, 0, stream>>>(ovf_cnt, ovf, feats, out);
  } else {
    // fallback: zero output, then direct atomic scatter
    int n4 = out_size / 4;
    pp_zero<<<2048, 256, 0, stream>>>((float4*)out, n4);
    int tblocks = (totalP * C_CH + 255) / 256;
    pp_direct<<<tblocks, 256, 0, stream>>>((const int2*)coords, feats, out,
                                           totalP, P);
  }
}